// Round 6
// baseline (1369.341 us; speedup 1.0000x reference)
//
#include <hip/hip_runtime.h>
#include <hip/hip_bf16.h>

#define NNODES   87381          // (4^9-1)/3
#define KIN      640
#define NOUTS    896
#define WC_ELEMS (NOUTS * KIN)  // 573440
// Wc layout: [dg=0..7][kt=0..19][cf=0..6][lane=0..63][j=0..7]  (bf16)
//   element: out = cf*128 + dg*16 + (lane&15),  k = kt*32 + (lane>>4)*8 + j
#define DG_STRIDE  71680        // 20*7*512 shorts
#define KT_STRIDE2 3584         // 7*512 shorts

typedef __attribute__((ext_vector_type(8))) unsigned short ushort8;
typedef __attribute__((ext_vector_type(4))) unsigned short ushort4v;
typedef __attribute__((ext_vector_type(8))) __bf16        bf16x8;
typedef __attribute__((ext_vector_type(4))) float         f32x4;

union Frag8 { ushort8 u; bf16x8 b; };

__device__ __forceinline__ unsigned short f2bf(float f) {
    unsigned int x = __float_as_uint(f);
    x += 0x7fffu + ((x >> 16) & 1u);          // round-to-nearest-even
    return (unsigned short)(x >> 16);
}
__device__ __forceinline__ float sigf(float x) {
    return __builtin_amdgcn_rcpf(1.0f + __expf(-x));
}
__device__ __forceinline__ float tanh_fast(float x) { return 2.0f * sigf(2.0f * x) - 1.0f; }

// ---------------- weight packing helpers ----------------
__device__ __forceinline__ unsigned short wc_elem(
    int idx, const float* __restrict__ W_iou, const float* __restrict__ U_iou,
    const float* __restrict__ W_f, const float* __restrict__ U_f)
{
    int dg = idx / DG_STRIDE;
    int r  = idx - dg * DG_STRIDE;
    int kt = r / KT_STRIDE2;
    int r2 = r - kt * KT_STRIDE2;
    int cf = r2 >> 9;
    int r3 = r2 & 511;
    int ln = r3 >> 3;
    int j  = r3 & 7;
    int out = cf * 128 + dg * 16 + (ln & 15);
    int k   = kt * 32 + ((ln >> 4) << 3) + j;
    float v;
    if (out < 384) {
        v = (k < 128) ? W_iou[out * 128 + k] : U_iou[(size_t)out * 512 + (k - 128)];
    } else {
        int o2 = out - 384;
        v = (k < 128) ? W_f[(o2 & 127) * 128 + k] : U_f[(size_t)o2 * 512 + (k - 128)];
    }
    return f2bf(v);
}

__device__ __forceinline__ void consts_row(
    int o, const float* __restrict__ U_iou, const float* __restrict__ U_f,
    const float* __restrict__ b_iou, const float* __restrict__ b_uiou,
    const float* __restrict__ b_wf,  const float* __restrict__ b_uf,
    const float* __restrict__ h0, float* __restrict__ biasc, float* __restrict__ hUc)
{
    float b = (o < 384) ? (b_iou[o] + b_uiou[o])
                        : (b_wf[(o - 384) & 127] + b_uf[o - 384]);
    const float* Urow = (o < 384) ? (U_iou + (size_t)o * 512)
                                  : (U_f + (size_t)(o - 384) * 512);
    float s0 = 0.f, s1 = 0.f;
    #pragma unroll 4
    for (int k = 0; k < 512; k += 8) {
        float4 u0 = *(const float4*)(Urow + k);
        float4 hv0 = *(const float4*)(h0 + k);
        float4 u1 = *(const float4*)(Urow + k + 4);
        float4 hv1 = *(const float4*)(h0 + k + 4);
        s0 += u0.x*hv0.x + u0.y*hv0.y + u0.z*hv0.z + u0.w*hv0.w;
        s1 += u1.x*hv1.x + u1.y*hv1.y + u1.z*hv1.z + u1.w*hv1.w;
    }
    biasc[o] = b;
    hUc[o]   = b + s0 + s1;
}

__global__ __launch_bounds__(256) void build_wc(
    const float* __restrict__ W_iou, const float* __restrict__ U_iou,
    const float* __restrict__ W_f,   const float* __restrict__ U_f,
    unsigned short* __restrict__ Wc)
{
    int idx = blockIdx.x * 256 + threadIdx.x;
    if (idx < WC_ELEMS) Wc[idx] = wc_elem(idx, W_iou, U_iou, W_f, U_f);
}

__global__ __launch_bounds__(64) void build_consts(
    const float* __restrict__ U_iou, const float* __restrict__ U_f,
    const float* __restrict__ b_iou, const float* __restrict__ b_uiou,
    const float* __restrict__ b_wf,  const float* __restrict__ b_uf,
    const float* __restrict__ h0,
    float* __restrict__ biasc, float* __restrict__ hUc)
{
    int o = blockIdx.x * 64 + threadIdx.x;
    if (o < NOUTS) consts_row(o, U_iou, U_f, b_iou, b_uiou, b_wf, b_uf, h0, biasc, hUc);
}

// ---------------- leaf unit: BM=32, K=128, full-N (wave wv = d-group) -------
__device__ __forceinline__ void leaf_unit32(
    const float* __restrict__ emb, const unsigned short* __restrict__ Wc,
    const float* __restrict__ hUc, const float* __restrict__ c0,
    float* __restrict__ outh, float* __restrict__ outc,
    unsigned short* __restrict__ hb, char* lds, int node0)
{
    const int tid = threadIdx.x;
    // stage 32x128 panel (2 stripes of 32x64, swizzled)
    {
        const int srow = tid >> 4;               // 0..31
        const int sc4  = (tid & 15) << 2;        // 0..60 step 4
        const float* src = emb + (size_t)(node0 + srow) * 128;
        const float4 v0 = *(const float4*)(src + sc4);
        const float4 v1 = *(const float4*)(src + 64 + sc4);
        const unsigned wby = (unsigned)((srow * 128 + sc4 * 2) ^ ((srow & 7) << 4));
        ushort4v w0, w1;
        w0[0] = f2bf(v0.x); w0[1] = f2bf(v0.y); w0[2] = f2bf(v0.z); w0[3] = f2bf(v0.w);
        w1[0] = f2bf(v1.x); w1[1] = f2bf(v1.y); w1[2] = f2bf(v1.z); w1[3] = f2bf(v1.w);
        *(ushort4v*)(lds + wby)        = w0;
        *(ushort4v*)(lds + 4096 + wby) = w1;
    }
    __syncthreads();

    const int wv = tid >> 6, ln = tid & 63, grp = ln >> 4, cl = ln & 15;
    const unsigned short* wbase = Wc + (size_t)wv * DG_STRIDE + (size_t)ln * 8;

    f32x4 acc[2][7] = {};
    #pragma unroll
    for (int kt = 0; kt < 4; ++kt) {
        const unsigned short* kp = wbase + kt * KT_STRIDE2;
        Frag8 bfr[7];
        #pragma unroll
        for (int cf = 0; cf < 7; ++cf)
            bfr[cf].u = *(const ushort8*)(kp + cf * 512);
        #pragma unroll
        for (int rf = 0; rf < 2; ++rf) {
            const int row = rf * 16 + cl;
            Frag8 afr;
            afr.u = *(const ushort8*)(lds + (kt >> 1) * 4096 + row * 128
                                      + (((kt & 1) * 64 + grp * 16) ^ ((row & 7) << 4)));
            #pragma unroll
            for (int cf = 0; cf < 7; ++cf)
                acc[rf][cf] = __builtin_amdgcn_mfma_f32_16x16x32_bf16(
                    afr.b, bfr[cf].b, acc[rf][cf], 0, 0, 0);
        }
    }

    // epilogue: leaf cell (h-part folded into hUc, c-in = c0)
    const int d = wv * 16 + cl;
    const float bi = hUc[d];
    const float bo = hUc[128 + d];
    const float bu = hUc[256 + d];
    float bfa[4], cin_leaf[4];
    #pragma unroll
    for (int a = 0; a < 4; ++a) { bfa[a] = hUc[384 + a * 128 + d]; cin_leaf[a] = c0[a * 128 + d]; }

    #pragma unroll
    for (int rf = 0; rf < 2; ++rf) {
        #pragma unroll
        for (int reg = 0; reg < 4; ++reg) {
            const int m = node0 + rf * 16 + grp * 4 + reg;
            const float i_ = acc[rf][0][reg] + bi;
            const float o_ = acc[rf][1][reg] + bo;
            const float u_ = acc[rf][2][reg] + bu;
            float c_ = sigf(i_) * tanh_fast(u_);
            #pragma unroll
            for (int a = 0; a < 4; ++a)
                c_ += sigf(acc[rf][3 + a][reg] + bfa[a]) * cin_leaf[a];
            const float h_ = sigf(o_) * tanh_fast(c_);
            const size_t oidx = (size_t)m * 128 + d;
            outh[oidx] = h_;
            outc[oidx] = c_;
            hb[oidx]   = f2bf(h_);
        }
    }
}

__global__ __launch_bounds__(512, 4) void tree_leaf32(
    const float* __restrict__ emb, const unsigned short* __restrict__ Wc,
    const float* __restrict__ hUc, const float* __restrict__ c0,
    float* __restrict__ outh, float* __restrict__ outc,
    unsigned short* __restrict__ hb)
{
    __shared__ __align__(16) char lds[8192];
    leaf_unit32(emb, Wc, hUc, c0, outh, outc, hb, lds, blockIdx.x * 32);
}

// ---------------- dsplit unit (non-leaf): 32 rows x one 16-col d-group ------
__device__ __forceinline__ void dsplit_unit(
    const float* __restrict__ emb, const unsigned short* __restrict__ Wc,
    const float* __restrict__ biasc,
    float* __restrict__ outh, float* __restrict__ outc,
    unsigned short* __restrict__ hb,
    char* lds, int n, int off, int cb, int mt, int dg)
{
    const int tid   = threadIdx.x;
    const int node0 = mt * 32;

    // stage A-panel [32][640] bf16: x from emb (f32+cvt), h from hb (bf16 copy)
    {
        const int srow = tid >> 4;              // 0..31
        const int sc4  = (tid & 15) << 2;       // 0..60 step 4
        int r = node0 + srow; if (r >= n) r = n - 1;
        const unsigned wby = (unsigned)((srow * 128 + sc4 * 2) ^ ((srow & 7) << 4));
        const float4 v0 = *(const float4*)(emb + (size_t)(off + r) * 128 + sc4);
        const float4 v1 = *(const float4*)(emb + (size_t)(off + r) * 128 + 64 + sc4);
        ushort4v w[10];
        #pragma unroll
        for (int i = 2; i < 10; ++i)
            w[i] = *(const ushort4v*)(hb + (size_t)(cb + 4 * r + ((i - 2) >> 1)) * 128
                                         + ((i - 2) & 1) * 64 + sc4);
        w[0][0] = f2bf(v0.x); w[0][1] = f2bf(v0.y); w[0][2] = f2bf(v0.z); w[0][3] = f2bf(v0.w);
        w[1][0] = f2bf(v1.x); w[1][1] = f2bf(v1.y); w[1][2] = f2bf(v1.z); w[1][3] = f2bf(v1.w);
        #pragma unroll
        for (int i = 0; i < 10; ++i)
            *(ushort4v*)(lds + i * 4096 + wby) = w[i];
    }
    __syncthreads();

    // barrier-free K-loop: wave = (rf, kq), 5 kt each
    const int wv  = tid >> 6;
    const int ln  = tid & 63;
    const int grp = ln >> 4;
    const int cl  = ln & 15;
    const int rf  = wv & 1;
    const int kq  = wv >> 1;
    const int row = rf * 16 + cl;
    const int swr = (row & 7) << 4;

    const unsigned short* wbase = Wc + (size_t)dg * DG_STRIDE + (size_t)ln * 8
                                     + (size_t)(kq * 5) * KT_STRIDE2;

    f32x4 acc[7] = {};
    #pragma unroll
    for (int t = 0; t < 5; ++t) {
        const int kt = kq * 5 + t;
        Frag8 afr;
        afr.u = *(const ushort8*)(lds + (kt >> 1) * 4096 + row * 128
                                  + (((kt & 1) * 64 + grp * 16) ^ swr));
        const unsigned short* kp = wbase + t * KT_STRIDE2;
        Frag8 bfr[7];
        #pragma unroll
        for (int cf = 0; cf < 7; ++cf)
            bfr[cf].u = *(const ushort8*)(kp + cf * 512);
        #pragma unroll
        for (int cf = 0; cf < 7; ++cf)
            acc[cf] = __builtin_amdgcn_mfma_f32_16x16x32_bf16(
                afr.b, bfr[cf].b, acc[cf], 0, 0, 0);
    }
    __syncthreads();                            // panel dead; LDS reused

    // cross-wave K reduction (slots for kq=1..3 only: 6*64*28*4 = 43008 B)
    float* red = (float*)lds;
    if (kq != 0) {
        const int slot = (((kq - 1) * 2 + rf) * 64 + ln) * 28;
        #pragma unroll
        for (int cf = 0; cf < 7; ++cf)
            *(f32x4*)(red + slot + cf * 4) = acc[cf];
    }
    __syncthreads();
    if (kq == 0) {
        #pragma unroll
        for (int q = 1; q < 4; ++q) {
            const int s2 = (((q - 1) * 2 + rf) * 64 + ln) * 28;
            #pragma unroll
            for (int cf = 0; cf < 7; ++cf)
                acc[cf] += *(const f32x4*)(red + s2 + cf * 4);
        }
        const int d = dg * 16 + cl;
        const float bi = biasc[d];
        const float bo = biasc[128 + d];
        const float bu = biasc[256 + d];
        float bfa[4];
        #pragma unroll
        for (int a = 0; a < 4; ++a) bfa[a] = biasc[384 + a * 128 + d];

        #pragma unroll
        for (int reg = 0; reg < 4; ++reg) {
            const int m = node0 + rf * 16 + grp * 4 + reg;
            if (m < n) {
                const float i_ = acc[0][reg] + bi;
                const float o_ = acc[1][reg] + bo;
                const float u_ = acc[2][reg] + bu;
                float c_ = sigf(i_) * tanh_fast(u_);
                #pragma unroll
                for (int a = 0; a < 4; ++a)
                    c_ += sigf(acc[3 + a][reg] + bfa[a]) * outc[(size_t)(cb + 4 * m + a) * 128 + d];
                const float h_ = sigf(o_) * tanh_fast(c_);
                const size_t oidx = (size_t)(off + m) * 128 + d;
                outh[oidx] = h_;
                outc[oidx] = c_;
                hb[oidx]   = f2bf(h_);
            }
        }
    }
}

__global__ __launch_bounds__(512, 4) void tree_dsplit(
    const float* __restrict__ emb, const unsigned short* __restrict__ Wc,
    const float* __restrict__ biasc,
    float* __restrict__ outh, float* __restrict__ outc,
    unsigned short* __restrict__ hb,
    int n, int off, int cb)
{
    __shared__ __align__(16) char lds[43008];
    dsplit_unit(emb, Wc, biasc, outh, outc, hb, lds, n, off, cb,
                blockIdx.x >> 3, blockIdx.x & 7);
}

// ---------------- custom device-scope generation barrier --------------------
__device__ __forceinline__ void gbar(unsigned* bar, unsigned nb) {
    __syncthreads();
    if (threadIdx.x == 0) {
        __threadfence();   // release all this block's prior writes
        unsigned g = __hip_atomic_load(bar + 1, __ATOMIC_RELAXED, __HIP_MEMORY_SCOPE_AGENT);
        unsigned a = __hip_atomic_fetch_add(bar, 1u, __ATOMIC_ACQ_REL, __HIP_MEMORY_SCOPE_AGENT);
        if (a == nb - 1u) {
            __hip_atomic_store(bar, 0u, __ATOMIC_RELAXED, __HIP_MEMORY_SCOPE_AGENT);
            __hip_atomic_fetch_add(bar + 1, 1u, __ATOMIC_ACQ_REL, __HIP_MEMORY_SCOPE_AGENT);
        } else {
            while (__hip_atomic_load(bar + 1, __ATOMIC_ACQUIRE, __HIP_MEMORY_SCOPE_AGENT) == g)
                __builtin_amdgcn_s_sleep(2);
        }
        __threadfence();   // acquire: invalidate stale cached lines
    }
    __syncthreads();
}

// ---------------- mega kernel: prep + leaf + all 8 upper levels -------------
__global__ __launch_bounds__(512, 4) void tree_mega(
    const float* __restrict__ emb,
    const float* __restrict__ W_iou, const float* __restrict__ U_iou,
    const float* __restrict__ W_f,   const float* __restrict__ U_f,
    const float* __restrict__ b_iou, const float* __restrict__ b_uiou,
    const float* __restrict__ b_wf,  const float* __restrict__ b_uf,
    const float* __restrict__ h0,    const float* __restrict__ c0,
    unsigned short* __restrict__ Wc, float* __restrict__ biasc, float* __restrict__ hUc,
    float* __restrict__ outh, float* __restrict__ outc,
    unsigned short* __restrict__ hb, unsigned* bar)
{
    __shared__ __align__(16) char lds[43008];
    const unsigned nb = gridDim.x;

    // phase 0: pack weights + consts
    for (int idx = blockIdx.x * 512 + threadIdx.x; idx < WC_ELEMS; idx += (int)nb * 512)
        Wc[idx] = wc_elem(idx, W_iou, U_iou, W_f, U_f);
    if (blockIdx.x < 2) {
        const int o = blockIdx.x * 512 + threadIdx.x;
        if (o < NOUTS)
            consts_row(o, U_iou, U_f, b_iou, b_uiou, b_wf, b_uf, h0, biasc, hUc);
    }
    gbar(bar, nb);

    // phase 1: leaf level (65536 nodes, 2048 units of 32 rows)
    for (int u = blockIdx.x; u < 2048; u += (int)nb) {
        leaf_unit32(emb, Wc, hUc, c0, outh, outc, hb, lds, u * 32);
        __syncthreads();
    }
    gbar(bar, nb);

    // phases 2..9: levels 7..0
    const int ns[8]    = {16384, 4096, 1024, 256, 64, 16, 4, 1};
    const int offs[8]  = {65536, 81920, 86016, 87040, 87296, 87360, 87376, 87380};
    const int cbs[8]   = {0, 65536, 81920, 86016, 87040, 87296, 87360, 87376};
    const int units[8] = {4096, 1024, 256, 64, 16, 8, 8, 8};
    #pragma unroll 1
    for (int li = 0; li < 8; ++li) {
        for (int u = blockIdx.x; u < units[li]; u += (int)nb) {
            dsplit_unit(emb, Wc, biasc, outh, outc, hb, lds,
                        ns[li], offs[li], cbs[li], u >> 3, u & 7);
            __syncthreads();
        }
        if (li < 7) gbar(bar, nb);
    }
}

extern "C" void kernel_launch(void* const* d_in, const int* in_sizes, int n_in,
                              void* d_out, int out_size, void* d_ws, size_t ws_size,
                              hipStream_t stream)
{
    const float* emb    = (const float*)d_in[0];
    const float* W_iou  = (const float*)d_in[1];
    const float* b_iou  = (const float*)d_in[2];
    const float* U_iou  = (const float*)d_in[3];
    const float* b_uiou = (const float*)d_in[4];
    const float* W_f    = (const float*)d_in[5];
    const float* b_wf   = (const float*)d_in[6];
    const float* U_f    = (const float*)d_in[7];
    const float* b_uf   = (const float*)d_in[8];
    const float* h0     = (const float*)d_in[9];
    const float* c0     = (const float*)d_in[10];

    char* ws = (char*)d_ws;
    unsigned short* Wc  = (unsigned short*)ws;                 // 1,146,880 B
    float* biasc        = (float*)(ws + 1146880);              // 3584 B
    float* hUc          = (float*)(ws + 1150464);              // 3584 B
    unsigned* bar       = (unsigned*)(ws + 1154048);           // 64 B
    unsigned short* hb  = (unsigned short*)(ws + 1154112);     // 22,369,536 B

    float* outh = (float*)d_out;
    float* outc = outh + (size_t)NNODES * 128;

    hipMemsetAsync(bar, 0, 64, stream);   // barrier state must start at 0

    const float* a_emb = emb;
    void* cargs[] = {
        (void*)&a_emb, (void*)&W_iou, (void*)&U_iou, (void*)&W_f, (void*)&U_f,
        (void*)&b_iou, (void*)&b_uiou, (void*)&b_wf, (void*)&b_uf,
        (void*)&h0, (void*)&c0,
        (void*)&Wc, (void*)&biasc, (void*)&hUc,
        (void*)&outh, (void*)&outc, (void*)&hb, (void*)&bar
    };
    hipError_t ce = hipLaunchCooperativeKernel((const void*)tree_mega,
                                               dim3(512), dim3(512), cargs, 0, stream);
    if (ce != hipSuccess) {
        (void)hipGetLastError();   // clear sticky error, use discrete launches
        hipLaunchKernelGGL(build_wc, dim3((WC_ELEMS + 255) / 256), dim3(256), 0, stream,
                           W_iou, U_iou, W_f, U_f, Wc);
        hipLaunchKernelGGL(build_consts, dim3((NOUTS + 63) / 64), dim3(64), 0, stream,
                           U_iou, U_f, b_iou, b_uiou, b_wf, b_uf, h0, biasc, hUc);
        hipLaunchKernelGGL(tree_leaf32, dim3(2048), dim3(512), 0, stream,
                           emb, Wc, hUc, c0, outh, outc, hb);
        const int ns[8]    = {16384, 4096, 1024, 256, 64, 16, 4, 1};
        const int offs[8]  = {65536, 81920, 86016, 87040, 87296, 87360, 87376, 87380};
        const int cbs[8]   = {0, 65536, 81920, 86016, 87040, 87296, 87360, 87376};
        const int units[8] = {4096, 1024, 256, 64, 16, 8, 8, 8};
        for (int li = 0; li < 8; ++li) {
            hipLaunchKernelGGL(tree_dsplit, dim3(units[li]), dim3(512), 0, stream,
                               emb, Wc, biasc, outh, outc, hb,
                               ns[li], offs[li], cbs[li]);
        }
    }
}

// Round 7
// 320.778 us; speedup vs baseline: 4.2688x; 4.2688x over previous
//
#include <hip/hip_runtime.h>
#include <hip/hip_bf16.h>

#define NNODES   87381          // (4^9-1)/3
#define KIN      640
#define NOUTS    896
#define WC_ELEMS (NOUTS * KIN)  // 573440
// Wc layout: [dg=0..7][kt=0..19][cf=0..6][lane=0..63][j=0..7]  (bf16)
//   element: out = cf*128 + dg*16 + (lane&15),  k = kt*32 + (lane>>4)*8 + j
#define DG_STRIDE  71680        // 20*7*512 shorts
#define KT_STRIDE2 3584         // 7*512 shorts

typedef __attribute__((ext_vector_type(8))) unsigned short ushort8;
typedef __attribute__((ext_vector_type(4))) unsigned short ushort4v;
typedef __attribute__((ext_vector_type(8))) __bf16        bf16x8;
typedef __attribute__((ext_vector_type(4))) float         f32x4;

union Frag8 { ushort8 u; bf16x8 b; };

__device__ __forceinline__ unsigned short f2bf(float f) {
    unsigned int x = __float_as_uint(f);
    x += 0x7fffu + ((x >> 16) & 1u);          // round-to-nearest-even
    return (unsigned short)(x >> 16);
}
__device__ __forceinline__ float sigf(float x) {
    return __builtin_amdgcn_rcpf(1.0f + __expf(-x));
}
__device__ __forceinline__ float tanh_fast(float x) { return 2.0f * sigf(2.0f * x) - 1.0f; }

// ---------------- weight packing (fragment-major, dg-major) ----------------
__global__ __launch_bounds__(512) void build_wc(
    const float* __restrict__ W_iou, const float* __restrict__ U_iou,
    const float* __restrict__ W_f,   const float* __restrict__ U_f,
    unsigned short* __restrict__ Wc)
{
    int idx = blockIdx.x * 512 + threadIdx.x;
    if (idx >= WC_ELEMS) return;
    int dg = idx / DG_STRIDE;
    int r  = idx - dg * DG_STRIDE;
    int kt = r / KT_STRIDE2;
    int r2 = r - kt * KT_STRIDE2;
    int cf = r2 >> 9;
    int r3 = r2 & 511;
    int ln = r3 >> 3;
    int j  = r3 & 7;
    int out = cf * 128 + dg * 16 + (ln & 15);
    int k   = kt * 32 + ((ln >> 4) << 3) + j;
    float v;
    if (out < 384) {
        v = (k < 128) ? W_iou[out * 128 + k] : U_iou[(size_t)out * 512 + (k - 128)];
    } else {
        int o2 = out - 384;
        v = (k < 128) ? W_f[(o2 & 127) * 128 + k] : U_f[(size_t)o2 * 512 + (k - 128)];
    }
    Wc[idx] = f2bf(v);
}

// wave-per-output-row: biasc[o] and hUc[o] = biasc[o] + (Uc . h0cat)[o]
__global__ __launch_bounds__(512) void build_consts(
    const float* __restrict__ U_iou, const float* __restrict__ U_f,
    const float* __restrict__ b_iou, const float* __restrict__ b_uiou,
    const float* __restrict__ b_wf,  const float* __restrict__ b_uf,
    const float* __restrict__ h0,
    float* __restrict__ biasc, float* __restrict__ hUc)
{
    const int o  = blockIdx.x * 8 + (threadIdx.x >> 6);
    const int ln = threadIdx.x & 63;
    if (o >= NOUTS) return;
    const float* Urow = (o < 384) ? (U_iou + (size_t)o * 512)
                                  : (U_f + (size_t)(o - 384) * 512);
    const float4 u0 = *(const float4*)(Urow + ln * 8);
    const float4 u1 = *(const float4*)(Urow + ln * 8 + 4);
    const float4 h0v = *(const float4*)(h0 + ln * 8);
    const float4 h1v = *(const float4*)(h0 + ln * 8 + 4);
    float s = u0.x*h0v.x + u0.y*h0v.y + u0.z*h0v.z + u0.w*h0v.w
            + u1.x*h1v.x + u1.y*h1v.y + u1.z*h1v.z + u1.w*h1v.w;
    #pragma unroll
    for (int w = 32; w >= 1; w >>= 1) s += __shfl_xor(s, w);
    if (ln == 0) {
        float b = (o < 384) ? (b_iou[o] + b_uiou[o])
                            : (b_wf[(o - 384) & 127] + b_uf[o - 384]);
        biasc[o] = b;
        hUc[o]   = b + s;
    }
}

// ---------------- leaf kernel (level 8): BM=32, K=128, wave = d-group -------
__global__ __launch_bounds__(512) void tree_leaf32(
    const float* __restrict__ emb, const unsigned short* __restrict__ Wc,
    const float* __restrict__ hUc, const float* __restrict__ c0,
    float* __restrict__ outh, float* __restrict__ outc,
    unsigned short* __restrict__ hb)
{
    __shared__ __align__(16) char lds[8192];
    const int tid   = threadIdx.x;
    const int node0 = blockIdx.x * 32;

    // stage 32x128 panel (2 stripes of 32x64, swizzled)
    {
        const int srow = tid >> 4;               // 0..31
        const int sc4  = (tid & 15) << 2;        // 0..60 step 4
        const float* src = emb + (size_t)(node0 + srow) * 128;
        const float4 v0 = *(const float4*)(src + sc4);
        const float4 v1 = *(const float4*)(src + 64 + sc4);
        const unsigned wby = (unsigned)((srow * 128 + sc4 * 2) ^ ((srow & 7) << 4));
        ushort4v w0, w1;
        w0[0] = f2bf(v0.x); w0[1] = f2bf(v0.y); w0[2] = f2bf(v0.z); w0[3] = f2bf(v0.w);
        w1[0] = f2bf(v1.x); w1[1] = f2bf(v1.y); w1[2] = f2bf(v1.z); w1[3] = f2bf(v1.w);
        *(ushort4v*)(lds + wby)        = w0;
        *(ushort4v*)(lds + 4096 + wby) = w1;
    }
    __syncthreads();

    const int wv = tid >> 6, ln = tid & 63, grp = ln >> 4, cl = ln & 15;
    const unsigned short* wbase = Wc + (size_t)wv * DG_STRIDE + (size_t)ln * 8;

    f32x4 acc[2][7] = {};
    #pragma unroll
    for (int kt = 0; kt < 4; ++kt) {
        const unsigned short* kp = wbase + kt * KT_STRIDE2;
        Frag8 bfr[7];
        #pragma unroll
        for (int cf = 0; cf < 7; ++cf)
            bfr[cf].u = *(const ushort8*)(kp + cf * 512);
        #pragma unroll
        for (int rf = 0; rf < 2; ++rf) {
            const int row = rf * 16 + cl;
            Frag8 afr;
            afr.u = *(const ushort8*)(lds + (kt >> 1) * 4096 + row * 128
                                      + (((kt & 1) * 64 + grp * 16) ^ ((row & 7) << 4)));
            #pragma unroll
            for (int cf = 0; cf < 7; ++cf)
                acc[rf][cf] = __builtin_amdgcn_mfma_f32_16x16x32_bf16(
                    afr.b, bfr[cf].b, acc[rf][cf], 0, 0, 0);
        }
    }

    const int d = wv * 16 + cl;
    const float bi = hUc[d];
    const float bo = hUc[128 + d];
    const float bu = hUc[256 + d];
    float bfa[4], cin_leaf[4];
    #pragma unroll
    for (int a = 0; a < 4; ++a) { bfa[a] = hUc[384 + a * 128 + d]; cin_leaf[a] = c0[a * 128 + d]; }

    #pragma unroll
    for (int rf = 0; rf < 2; ++rf) {
        #pragma unroll
        for (int reg = 0; reg < 4; ++reg) {
            const int m = node0 + rf * 16 + grp * 4 + reg;
            const float i_ = acc[rf][0][reg] + bi;
            const float o_ = acc[rf][1][reg] + bo;
            const float u_ = acc[rf][2][reg] + bu;
            float c_ = sigf(i_) * tanh_fast(u_);
            #pragma unroll
            for (int a = 0; a < 4; ++a)
                c_ += sigf(acc[rf][3 + a][reg] + bfa[a]) * cin_leaf[a];
            const float h_ = sigf(o_) * tanh_fast(c_);
            const size_t oidx = (size_t)m * 128 + d;
            outh[oidx] = h_;
            outc[oidx] = c_;
            hb[oidx]   = f2bf(h_);
        }
    }
}

// ---------------- dsplit (non-leaf, levels 7..3): 32 rows x one d-group -----
__global__ __launch_bounds__(512) void tree_dsplit(
    const float* __restrict__ emb, const unsigned short* __restrict__ Wc,
    const float* __restrict__ biasc,
    float* __restrict__ outh, float* __restrict__ outc,
    unsigned short* __restrict__ hb,
    int n, int off, int cb)
{
    __shared__ __align__(16) char lds[43008];
    const int tid   = threadIdx.x;
    const int mt    = blockIdx.x >> 3;
    const int dg    = blockIdx.x & 7;
    const int node0 = mt * 32;

    // stage A-panel [32][640] bf16: x from emb (f32+cvt), h from hb (bf16 copy)
    {
        const int srow = tid >> 4;              // 0..31
        const int sc4  = (tid & 15) << 2;       // 0..60 step 4
        int r = node0 + srow; if (r >= n) r = n - 1;
        const unsigned wby = (unsigned)((srow * 128 + sc4 * 2) ^ ((srow & 7) << 4));
        const float4 v0 = *(const float4*)(emb + (size_t)(off + r) * 128 + sc4);
        const float4 v1 = *(const float4*)(emb + (size_t)(off + r) * 128 + 64 + sc4);
        ushort4v w[10];
        #pragma unroll
        for (int i = 2; i < 10; ++i)
            w[i] = *(const ushort4v*)(hb + (size_t)(cb + 4 * r + ((i - 2) >> 1)) * 128
                                         + ((i - 2) & 1) * 64 + sc4);
        w[0][0] = f2bf(v0.x); w[0][1] = f2bf(v0.y); w[0][2] = f2bf(v0.z); w[0][3] = f2bf(v0.w);
        w[1][0] = f2bf(v1.x); w[1][1] = f2bf(v1.y); w[1][2] = f2bf(v1.z); w[1][3] = f2bf(v1.w);
        #pragma unroll
        for (int i = 0; i < 10; ++i)
            *(ushort4v*)(lds + i * 4096 + wby) = w[i];
    }
    __syncthreads();

    // barrier-free K-loop: wave = (rf, kq), 5 kt each
    const int wv  = tid >> 6;
    const int ln  = tid & 63;
    const int grp = ln >> 4;
    const int cl  = ln & 15;
    const int rf  = wv & 1;
    const int kq  = wv >> 1;
    const int row = rf * 16 + cl;
    const int swr = (row & 7) << 4;

    const unsigned short* wbase = Wc + (size_t)dg * DG_STRIDE + (size_t)ln * 8
                                     + (size_t)(kq * 5) * KT_STRIDE2;

    f32x4 acc[7] = {};
    #pragma unroll
    for (int t = 0; t < 5; ++t) {
        const int kt = kq * 5 + t;
        Frag8 afr;
        afr.u = *(const ushort8*)(lds + (kt >> 1) * 4096 + row * 128
                                  + (((kt & 1) * 64 + grp * 16) ^ swr));
        const unsigned short* kp = wbase + t * KT_STRIDE2;
        Frag8 bfr[7];
        #pragma unroll
        for (int cf = 0; cf < 7; ++cf)
            bfr[cf].u = *(const ushort8*)(kp + cf * 512);
        #pragma unroll
        for (int cf = 0; cf < 7; ++cf)
            acc[cf] = __builtin_amdgcn_mfma_f32_16x16x32_bf16(
                afr.b, bfr[cf].b, acc[cf], 0, 0, 0);
    }
    __syncthreads();                            // panel dead; LDS reused

    // cross-wave K reduction (slots for kq=1..3: 6*64*28*4 = 43008 B)
    float* red = (float*)lds;
    if (kq != 0) {
        const int slot = (((kq - 1) * 2 + rf) * 64 + ln) * 28;
        #pragma unroll
        for (int cf = 0; cf < 7; ++cf)
            *(f32x4*)(red + slot + cf * 4) = acc[cf];
    }
    __syncthreads();
    if (kq == 0) {
        #pragma unroll
        for (int q = 1; q < 4; ++q) {
            const int s2 = (((q - 1) * 2 + rf) * 64 + ln) * 28;
            #pragma unroll
            for (int cf = 0; cf < 7; ++cf)
                acc[cf] += *(const f32x4*)(red + s2 + cf * 4);
        }
        const int d = dg * 16 + cl;
        const float bi = biasc[d];
        const float bo = biasc[128 + d];
        const float bu = biasc[256 + d];
        float bfa[4];
        #pragma unroll
        for (int a = 0; a < 4; ++a) bfa[a] = biasc[384 + a * 128 + d];

        #pragma unroll
        for (int reg = 0; reg < 4; ++reg) {
            const int m = node0 + rf * 16 + grp * 4 + reg;
            if (m < n) {
                const float i_ = acc[0][reg] + bi;
                const float o_ = acc[1][reg] + bo;
                const float u_ = acc[2][reg] + bu;
                float c_ = sigf(i_) * tanh_fast(u_);
                #pragma unroll
                for (int a = 0; a < 4; ++a)
                    c_ += sigf(acc[3 + a][reg] + bfa[a]) * outc[(size_t)(cb + 4 * m + a) * 128 + d];
                const float h_ = sigf(o_) * tanh_fast(c_);
                const size_t oidx = (size_t)(off + m) * 128 + d;
                outh[oidx] = h_;
                outc[oidx] = c_;
                hb[oidx]   = f2bf(h_);
            }
        }
    }
}

// ---------------- tail: levels 2..0 (n=16,4,1) in ONE block -----------------
// 8 waves; wave wv owns d-group wv, computes full K=640 serially (no split-K).
__global__ __launch_bounds__(512) void tree_tail3(
    const float* __restrict__ emb, const unsigned short* __restrict__ Wc,
    const float* __restrict__ biasc,
    float* __restrict__ outh, float* __restrict__ outc,
    unsigned short* __restrict__ hb)
{
    __shared__ __align__(16) char lds[40960];
    const int ns[3]   = {16, 4, 1};
    const int offs[3] = {87360, 87376, 87380};
    const int cbs[3]  = {87296, 87360, 87376};

    const int tid = threadIdx.x;
    const int wv = tid >> 6, ln = tid & 63, grp = ln >> 4, cl = ln & 15;

    #pragma unroll 1
    for (int li = 0; li < 3; ++li) {
        const int n = ns[li], off = offs[li], cb = cbs[li];

        // stage 16 rows x 640 (threads 0..255), same stripe layout as dsplit
        if (tid < 256) {
            const int srow = tid >> 4;          // 0..15
            const int sc4  = (tid & 15) << 2;   // 0..60 step 4
            int r = srow; if (r >= n) r = n - 1;
            const unsigned wby = (unsigned)((srow * 128 + sc4 * 2) ^ ((srow & 7) << 4));
            const float4 v0 = *(const float4*)(emb + (size_t)(off + r) * 128 + sc4);
            const float4 v1 = *(const float4*)(emb + (size_t)(off + r) * 128 + 64 + sc4);
            ushort4v w0, w1;
            w0[0] = f2bf(v0.x); w0[1] = f2bf(v0.y); w0[2] = f2bf(v0.z); w0[3] = f2bf(v0.w);
            w1[0] = f2bf(v1.x); w1[1] = f2bf(v1.y); w1[2] = f2bf(v1.z); w1[3] = f2bf(v1.w);
            *(ushort4v*)(lds + wby)        = w0;
            *(ushort4v*)(lds + 4096 + wby) = w1;
            #pragma unroll
            for (int i = 2; i < 10; ++i) {
                ushort4v w = *(const ushort4v*)(hb + (size_t)(cb + 4 * r + ((i - 2) >> 1)) * 128
                                                   + ((i - 2) & 1) * 64 + sc4);
                *(ushort4v*)(lds + i * 4096 + wby) = w;
            }
        }
        __syncthreads();

        const unsigned short* wbase = Wc + (size_t)wv * DG_STRIDE + (size_t)ln * 8;
        f32x4 acc[7] = {};
        #pragma unroll 2
        for (int kt = 0; kt < 20; ++kt) {
            Frag8 afr;
            afr.u = *(const ushort8*)(lds + (kt >> 1) * 4096 + cl * 128
                                      + (((kt & 1) * 64 + grp * 16) ^ ((cl & 7) << 4)));
            const unsigned short* kp = wbase + kt * KT_STRIDE2;
            Frag8 bfr[7];
            #pragma unroll
            for (int cf = 0; cf < 7; ++cf)
                bfr[cf].u = *(const ushort8*)(kp + cf * 512);
            #pragma unroll
            for (int cf = 0; cf < 7; ++cf)
                acc[cf] = __builtin_amdgcn_mfma_f32_16x16x32_bf16(
                    afr.b, bfr[cf].b, acc[cf], 0, 0, 0);
        }

        const int d = wv * 16 + cl;
        const float bi = biasc[d];
        const float bo = biasc[128 + d];
        const float bu = biasc[256 + d];
        float bfa[4];
        #pragma unroll
        for (int a = 0; a < 4; ++a) bfa[a] = biasc[384 + a * 128 + d];

        #pragma unroll
        for (int reg = 0; reg < 4; ++reg) {
            const int m = grp * 4 + reg;
            if (m < n) {
                const float i_ = acc[0][reg] + bi;
                const float o_ = acc[1][reg] + bo;
                const float u_ = acc[2][reg] + bu;
                float c_ = sigf(i_) * tanh_fast(u_);
                #pragma unroll
                for (int a = 0; a < 4; ++a)
                    c_ += sigf(acc[3 + a][reg] + bfa[a]) * outc[(size_t)(cb + 4 * m + a) * 128 + d];
                const float h_ = sigf(o_) * tanh_fast(c_);
                const size_t oidx = (size_t)(off + m) * 128 + d;
                outh[oidx] = h_;
                outc[oidx] = c_;
                hb[oidx]   = f2bf(h_);
            }
        }
        __threadfence();       // writes visible before next level's staging
        __syncthreads();
    }
}

extern "C" void kernel_launch(void* const* d_in, const int* in_sizes, int n_in,
                              void* d_out, int out_size, void* d_ws, size_t ws_size,
                              hipStream_t stream)
{
    const float* emb    = (const float*)d_in[0];
    const float* W_iou  = (const float*)d_in[1];
    const float* b_iou  = (const float*)d_in[2];
    const float* U_iou  = (const float*)d_in[3];
    const float* b_uiou = (const float*)d_in[4];
    const float* W_f    = (const float*)d_in[5];
    const float* b_wf   = (const float*)d_in[6];
    const float* U_f    = (const float*)d_in[7];
    const float* b_uf   = (const float*)d_in[8];
    const float* h0     = (const float*)d_in[9];
    const float* c0     = (const float*)d_in[10];

    char* ws = (char*)d_ws;
    unsigned short* Wc  = (unsigned short*)ws;                 // 1,146,880 B
    float* biasc        = (float*)(ws + 1146880);              // 3584 B
    float* hUc          = (float*)(ws + 1150464);              // 3584 B
    unsigned short* hb  = (unsigned short*)(ws + 1154112);     // 22,369,536 B

    float* outh = (float*)d_out;
    float* outc = outh + (size_t)NNODES * 128;

    hipLaunchKernelGGL(build_wc, dim3((WC_ELEMS + 511) / 512), dim3(512), 0, stream,
                       W_iou, U_iou, W_f, U_f, Wc);
    hipLaunchKernelGGL(build_consts, dim3(NOUTS / 8), dim3(512), 0, stream,
                       U_iou, U_f, b_iou, b_uiou, b_wf, b_uf, h0, biasc, hUc);

    // level 8 (leaf): 65536 nodes, BM=32
    hipLaunchKernelGGL(tree_leaf32, dim3(2048), dim3(512), 0, stream,
                       emb, Wc, hUc, c0, outh, outc, hb);

    // levels 7..3 via dsplit
    const int ns[5]   = {16384, 4096, 1024, 256, 64};
    const int offs[5] = {65536, 81920, 86016, 87040, 87296};
    const int cbs[5]  = {0, 65536, 81920, 86016, 87040};
    for (int li = 0; li < 5; ++li) {
        const int units = (ns[li] / 32) * 8;
        hipLaunchKernelGGL(tree_dsplit, dim3(units), dim3(512), 0, stream,
                           emb, Wc, biasc, outh, outc, hb,
                           ns[li], offs[li], cbs[li]);
    }

    // levels 2..0 in one block
    hipLaunchKernelGGL(tree_tail3, dim3(1), dim3(512), 0, stream,
                       emb, Wc, biasc, outh, outc, hb);
}

// Round 8
// 294.449 us; speedup vs baseline: 4.6505x; 1.0894x over previous
//
#include <hip/hip_runtime.h>
#include <hip/hip_bf16.h>

#define NNODES   87381          // (4^9-1)/3
#define KIN      640
#define NOUTS    896
#define WC_ELEMS (NOUTS * KIN)  // 573440
// Wc layout: [dg=0..7][kt=0..19][cf=0..6][lane=0..63][j=0..7]  (bf16)
//   element: out = cf*128 + dg*16 + (lane&15),  k = kt*32 + (lane>>4)*8 + j
#define DG_STRIDE  71680        // 20*7*512 shorts
#define KT_STRIDE2 3584         // 7*512 shorts

typedef __attribute__((ext_vector_type(8))) unsigned short ushort8;
typedef __attribute__((ext_vector_type(8))) __bf16        bf16x8;
typedef __attribute__((ext_vector_type(4))) float         f32x4;

union Frag8 { ushort8 u; bf16x8 b; };

__device__ __forceinline__ unsigned short f2bf(float f) {
    unsigned int x = __float_as_uint(f);
    x += 0x7fffu + ((x >> 16) & 1u);          // round-to-nearest-even
    return (unsigned short)(x >> 16);
}
__device__ __forceinline__ float sigf(float x) {
    return __builtin_amdgcn_rcpf(1.0f + __expf(-x));
}
__device__ __forceinline__ float tanh_fast(float x) { return 2.0f * sigf(2.0f * x) - 1.0f; }

__device__ __forceinline__ ushort8 pack8(const float4& v0, const float4& v1) {
    ushort8 w;
    w[0] = f2bf(v0.x); w[1] = f2bf(v0.y); w[2] = f2bf(v0.z); w[3] = f2bf(v0.w);
    w[4] = f2bf(v1.x); w[5] = f2bf(v1.y); w[6] = f2bf(v1.z); w[7] = f2bf(v1.w);
    return w;
}

// ---------------- prep: Wc pack (blocks 0..1119) + consts (blocks 1120..1231)
__global__ __launch_bounds__(512) void prep(
    const float* __restrict__ W_iou, const float* __restrict__ U_iou,
    const float* __restrict__ W_f,   const float* __restrict__ U_f,
    const float* __restrict__ b_iou, const float* __restrict__ b_uiou,
    const float* __restrict__ b_wf,  const float* __restrict__ b_uf,
    const float* __restrict__ h0,
    unsigned short* __restrict__ Wc, float* __restrict__ biasc, float* __restrict__ hUc)
{
    if (blockIdx.x < 1120) {
        int idx = blockIdx.x * 512 + threadIdx.x;     // < 573440 exactly
        int dg = idx / DG_STRIDE;
        int r  = idx - dg * DG_STRIDE;
        int kt = r / KT_STRIDE2;
        int r2 = r - kt * KT_STRIDE2;
        int cf = r2 >> 9;
        int r3 = r2 & 511;
        int ln = r3 >> 3;
        int j  = r3 & 7;
        int out = cf * 128 + dg * 16 + (ln & 15);
        int k   = kt * 32 + ((ln >> 4) << 3) + j;
        float v;
        if (out < 384) {
            v = (k < 128) ? W_iou[out * 128 + k] : U_iou[(size_t)out * 512 + (k - 128)];
        } else {
            int o2 = out - 384;
            v = (k < 128) ? W_f[(o2 & 127) * 128 + k] : U_f[(size_t)o2 * 512 + (k - 128)];
        }
        Wc[idx] = f2bf(v);
    } else {
        const int o  = (blockIdx.x - 1120) * 8 + (threadIdx.x >> 6);
        const int ln = threadIdx.x & 63;
        if (o >= NOUTS) return;
        const float* Urow = (o < 384) ? (U_iou + (size_t)o * 512)
                                      : (U_f + (size_t)(o - 384) * 512);
        const float4 u0 = *(const float4*)(Urow + ln * 8);
        const float4 u1 = *(const float4*)(Urow + ln * 8 + 4);
        const float4 h0v = *(const float4*)(h0 + ln * 8);
        const float4 h1v = *(const float4*)(h0 + ln * 8 + 4);
        float s = u0.x*h0v.x + u0.y*h0v.y + u0.z*h0v.z + u0.w*h0v.w
                + u1.x*h1v.x + u1.y*h1v.y + u1.z*h1v.z + u1.w*h1v.w;
        #pragma unroll
        for (int w = 32; w >= 1; w >>= 1) s += __shfl_xor(s, w);
        if (ln == 0) {
            float b = (o < 384) ? (b_iou[o] + b_uiou[o])
                                : (b_wf[(o - 384) & 127] + b_uf[o - 384]);
            biasc[o] = b;
            hUc[o]   = b + s;
        }
    }
}

// ---------------- leaf kernel (level 8): BM=32, K=128, wave = d-group -------
__global__ __launch_bounds__(512) void tree_leaf32(
    const float* __restrict__ emb, const unsigned short* __restrict__ Wc,
    const float* __restrict__ hUc, const float* __restrict__ c0,
    float* __restrict__ outh, float* __restrict__ outc,
    unsigned short* __restrict__ hb)
{
    __shared__ __align__(16) char lds[8192];
    const int tid   = threadIdx.x;
    const int node0 = blockIdx.x * 32;

    // stage 32x128 panel: 1 ushort8 chunk per thread
    {
        const int srow = tid >> 4;               // 0..31
        const int q    = tid & 15;               // chunk of 8 elems
        const float* src = emb + (size_t)(node0 + srow) * 128 + q * 8;
        const float4 v0 = *(const float4*)src;
        const float4 v1 = *(const float4*)(src + 4);
        const int stripe = q >> 3;
        const unsigned by = (unsigned)((srow * 128 + (q & 7) * 16) ^ ((srow & 7) << 4));
        *(ushort8*)(lds + stripe * 4096 + by) = pack8(v0, v1);
    }
    __syncthreads();

    const int wv = tid >> 6, ln = tid & 63, grp = ln >> 4, cl = ln & 15;
    const unsigned short* wbase = Wc + (size_t)wv * DG_STRIDE + (size_t)ln * 8;

    f32x4 acc[2][7] = {};
    #pragma unroll
    for (int kt = 0; kt < 4; ++kt) {
        const unsigned short* kp = wbase + kt * KT_STRIDE2;
        Frag8 bfr[7];
        #pragma unroll
        for (int cf = 0; cf < 7; ++cf)
            bfr[cf].u = *(const ushort8*)(kp + cf * 512);
        #pragma unroll
        for (int rf = 0; rf < 2; ++rf) {
            const int row = rf * 16 + cl;
            Frag8 afr;
            afr.u = *(const ushort8*)(lds + (kt >> 1) * 4096 + row * 128
                                      + (((kt & 1) * 64 + grp * 16) ^ ((row & 7) << 4)));
            #pragma unroll
            for (int cf = 0; cf < 7; ++cf)
                acc[rf][cf] = __builtin_amdgcn_mfma_f32_16x16x32_bf16(
                    afr.b, bfr[cf].b, acc[rf][cf], 0, 0, 0);
        }
    }

    const int d = wv * 16 + cl;
    const float bi = hUc[d];
    const float bo = hUc[128 + d];
    const float bu = hUc[256 + d];
    float bfa[4], cin_leaf[4];
    #pragma unroll
    for (int a = 0; a < 4; ++a) { bfa[a] = hUc[384 + a * 128 + d]; cin_leaf[a] = c0[a * 128 + d]; }

    #pragma unroll
    for (int rf = 0; rf < 2; ++rf) {
        #pragma unroll
        for (int reg = 0; reg < 4; ++reg) {
            const int m = node0 + rf * 16 + grp * 4 + reg;
            const float i_ = acc[rf][0][reg] + bi;
            const float o_ = acc[rf][1][reg] + bo;
            const float u_ = acc[rf][2][reg] + bu;
            float c_ = sigf(i_) * tanh_fast(u_);
            #pragma unroll
            for (int a = 0; a < 4; ++a)
                c_ += sigf(acc[rf][3 + a][reg] + bfa[a]) * cin_leaf[a];
            const float h_ = sigf(o_) * tanh_fast(c_);
            const size_t oidx = (size_t)m * 128 + d;
            outh[oidx] = h_;
            outc[oidx] = c_;
            hb[oidx]   = f2bf(h_);
        }
    }
}

// ---------------- dsplit (non-leaf): 32 rows x one d-group, XCD-grouped -----
__global__ __launch_bounds__(512) void tree_dsplit(
    const float* __restrict__ emb, const unsigned short* __restrict__ Wc,
    const float* __restrict__ biasc,
    float* __restrict__ outh, float* __restrict__ outc,
    unsigned short* __restrict__ hb,
    int n, int off, int cb)
{
    __shared__ __align__(16) char lds[43008];
    const int tid = threadIdx.x;
    const int nmt = n >> 5;

    // XCD-aware mapping: all 8 dg-blocks of one mt land on the SAME XCD
    int mt, dg;
    if (nmt >= 8) {
        const int xcd = blockIdx.x & 7;
        const int j   = blockIdx.x >> 3;        // 0..nmt-1
        mt = xcd * (nmt >> 3) + (j >> 3);
        dg = j & 7;
    } else {
        mt = blockIdx.x >> 3;
        dg = blockIdx.x & 7;
    }
    const int node0 = mt * 32;

    // stage A-panel [32][640] bf16: chunk 0 = x (f32+cvt), chunks 1..4 = hb copy
    {
        const int srow = tid >> 4;              // 0..31
        const int q    = tid & 15;
        int r = node0 + srow; if (r >= n) r = n - 1;
        const unsigned sx = (unsigned)((srow & 7) << 4);
        {
            const float* s = emb + (size_t)(off + r) * 128 + q * 8;
            const float4 v0 = *(const float4*)s;
            const float4 v1 = *(const float4*)(s + 4);
            const int stripe = q >> 3;
            const unsigned by = (unsigned)((srow * 128 + (q & 7) * 16) ^ sx);
            *(ushort8*)(lds + stripe * 4096 + by) = pack8(v0, v1);
        }
        #pragma unroll
        for (int c = 1; c < 5; ++c) {
            const int e = c * 128 + q * 8;      // 128..632
            const int child = (e - 128) >> 7;
            const int d0    = (e - 128) & 127;
            ushort8 w = *(const ushort8*)(hb + (size_t)(cb + 4 * r + child) * 128 + d0);
            const int stripe = e >> 6;
            const unsigned by = (unsigned)((srow * 128 + (e & 63) * 2) ^ sx);
            *(ushort8*)(lds + stripe * 4096 + by) = w;
        }
    }
    __syncthreads();

    // barrier-free K-loop: wave = (rf, kq), 5 kt each, B-loads double-buffered
    const int wv  = tid >> 6;
    const int ln  = tid & 63;
    const int grp = ln >> 4;
    const int cl  = ln & 15;
    const int rf  = wv & 1;
    const int kq  = wv >> 1;
    const int row = rf * 16 + cl;
    const int swr = (row & 7) << 4;

    const unsigned short* wbase = Wc + (size_t)dg * DG_STRIDE + (size_t)ln * 8
                                     + (size_t)(kq * 5) * KT_STRIDE2;

    Frag8 bb[2][7];
    #pragma unroll
    for (int cf = 0; cf < 7; ++cf)
        bb[0][cf].u = *(const ushort8*)(wbase + cf * 512);

    f32x4 acc[7] = {};
    #pragma unroll
    for (int t = 0; t < 5; ++t) {
        const int cur = t & 1, nxt = cur ^ 1;
        if (t < 4) {
            const unsigned short* kp = wbase + (t + 1) * KT_STRIDE2;
            #pragma unroll
            for (int cf = 0; cf < 7; ++cf)
                bb[nxt][cf].u = *(const ushort8*)(kp + cf * 512);
        }
        const int kt = kq * 5 + t;
        Frag8 afr;
        afr.u = *(const ushort8*)(lds + (kt >> 1) * 4096 + row * 128
                                  + (((kt & 1) * 64 + grp * 16) ^ swr));
        #pragma unroll
        for (int cf = 0; cf < 7; ++cf)
            acc[cf] = __builtin_amdgcn_mfma_f32_16x16x32_bf16(
                afr.b, bb[cur][cf].b, acc[cf], 0, 0, 0);
    }
    __syncthreads();                            // panel dead; LDS reused

    // cross-wave K reduction (slots for kq=1..3: 6*64*28*4 = 43008 B)
    float* red = (float*)lds;
    if (kq != 0) {
        const int slot = (((kq - 1) * 2 + rf) * 64 + ln) * 28;
        #pragma unroll
        for (int cf = 0; cf < 7; ++cf)
            *(f32x4*)(red + slot + cf * 4) = acc[cf];
    }
    __syncthreads();
    if (kq == 0) {
        #pragma unroll
        for (int q = 1; q < 4; ++q) {
            const int s2 = (((q - 1) * 2 + rf) * 64 + ln) * 28;
            #pragma unroll
            for (int cf = 0; cf < 7; ++cf)
                acc[cf] += *(const f32x4*)(red + s2 + cf * 4);
        }
        const int d = dg * 16 + cl;
        const float bi = biasc[d];
        const float bo = biasc[128 + d];
        const float bu = biasc[256 + d];
        float bfa[4];
        #pragma unroll
        for (int a = 0; a < 4; ++a) bfa[a] = biasc[384 + a * 128 + d];

        #pragma unroll
        for (int reg = 0; reg < 4; ++reg) {
            const int m = node0 + rf * 16 + grp * 4 + reg;
            if (m < n) {
                const float i_ = acc[0][reg] + bi;
                const float o_ = acc[1][reg] + bo;
                const float u_ = acc[2][reg] + bu;
                float c_ = sigf(i_) * tanh_fast(u_);
                #pragma unroll
                for (int a = 0; a < 4; ++a)
                    c_ += sigf(acc[3 + a][reg] + bfa[a]) * outc[(size_t)(cb + 4 * m + a) * 128 + d];
                const float h_ = sigf(o_) * tanh_fast(c_);
                const size_t oidx = (size_t)(off + m) * 128 + d;
                outh[oidx] = h_;
                outc[oidx] = c_;
                hb[oidx]   = f2bf(h_);
            }
        }
    }
}

// ---------------- tail: levels 2..0 (n=16,4,1) in ONE block -----------------
__global__ __launch_bounds__(512) void tree_tail3(
    const float* __restrict__ emb, const unsigned short* __restrict__ Wc,
    const float* __restrict__ biasc,
    float* __restrict__ outh, float* __restrict__ outc,
    unsigned short* __restrict__ hb)
{
    __shared__ __align__(16) char lds[40960];
    const int ns[3]   = {16, 4, 1};
    const int offs[3] = {87360, 87376, 87380};
    const int cbs[3]  = {87296, 87360, 87376};

    const int tid = threadIdx.x;
    const int wv = tid >> 6, ln = tid & 63, grp = ln >> 4, cl = ln & 15;

    #pragma unroll 1
    for (int li = 0; li < 3; ++li) {
        const int n = ns[li], off = offs[li], cb = cbs[li];

        if (tid < 256) {
            const int srow = tid >> 4;          // 0..15
            const int q    = tid & 15;
            int r = srow; if (r >= n) r = n - 1;
            const unsigned sx = (unsigned)((srow & 7) << 4);
            {
                const float* s = emb + (size_t)(off + r) * 128 + q * 8;
                const float4 v0 = *(const float4*)s;
                const float4 v1 = *(const float4*)(s + 4);
                const unsigned by = (unsigned)((srow * 128 + (q & 7) * 16) ^ sx);
                *(ushort8*)(lds + (q >> 3) * 4096 + by) = pack8(v0, v1);
            }
            #pragma unroll
            for (int c = 1; c < 5; ++c) {
                const int e = c * 128 + q * 8;
                const int child = (e - 128) >> 7;
                const int d0    = (e - 128) & 127;
                ushort8 w = *(const ushort8*)(hb + (size_t)(cb + 4 * r + child) * 128 + d0);
                const unsigned by = (unsigned)((srow * 128 + (e & 63) * 2) ^ sx);
                *(ushort8*)(lds + (e >> 6) * 4096 + by) = w;
            }
        }
        __syncthreads();

        const unsigned short* wbase = Wc + (size_t)wv * DG_STRIDE + (size_t)ln * 8;
        f32x4 acc[7] = {};
        #pragma unroll 2
        for (int kt = 0; kt < 20; ++kt) {
            Frag8 afr;
            afr.u = *(const ushort8*)(lds + (kt >> 1) * 4096 + cl * 128
                                      + (((kt & 1) * 64 + grp * 16) ^ ((cl & 7) << 4)));
            const unsigned short* kp = wbase + kt * KT_STRIDE2;
            Frag8 bfr[7];
            #pragma unroll
            for (int cf = 0; cf < 7; ++cf)
                bfr[cf].u = *(const ushort8*)(kp + cf * 512);
            #pragma unroll
            for (int cf = 0; cf < 7; ++cf)
                acc[cf] = __builtin_amdgcn_mfma_f32_16x16x32_bf16(
                    afr.b, bfr[cf].b, acc[cf], 0, 0, 0);
        }

        const int d = wv * 16 + cl;
        const float bi = biasc[d];
        const float bo = biasc[128 + d];
        const float bu = biasc[256 + d];
        float bfa[4];
        #pragma unroll
        for (int a = 0; a < 4; ++a) bfa[a] = biasc[384 + a * 128 + d];

        #pragma unroll
        for (int reg = 0; reg < 4; ++reg) {
            const int m = grp * 4 + reg;
            if (m < n) {
                const float i_ = acc[0][reg] + bi;
                const float o_ = acc[1][reg] + bo;
                const float u_ = acc[2][reg] + bu;
                float c_ = sigf(i_) * tanh_fast(u_);
                #pragma unroll
                for (int a = 0; a < 4; ++a)
                    c_ += sigf(acc[3 + a][reg] + bfa[a]) * outc[(size_t)(cb + 4 * m + a) * 128 + d];
                const float h_ = sigf(o_) * tanh_fast(c_);
                const size_t oidx = (size_t)(off + m) * 128 + d;
                outh[oidx] = h_;
                outc[oidx] = c_;
                hb[oidx]   = f2bf(h_);
            }
        }
        __threadfence();       // writes visible before next level's staging
        __syncthreads();
    }
}

extern "C" void kernel_launch(void* const* d_in, const int* in_sizes, int n_in,
                              void* d_out, int out_size, void* d_ws, size_t ws_size,
                              hipStream_t stream)
{
    const float* emb    = (const float*)d_in[0];
    const float* W_iou  = (const float*)d_in[1];
    const float* b_iou  = (const float*)d_in[2];
    const float* U_iou  = (const float*)d_in[3];
    const float* b_uiou = (const float*)d_in[4];
    const float* W_f    = (const float*)d_in[5];
    const float* b_wf   = (const float*)d_in[6];
    const float* U_f    = (const float*)d_in[7];
    const float* b_uf   = (const float*)d_in[8];
    const float* h0     = (const float*)d_in[9];
    const float* c0     = (const float*)d_in[10];

    char* ws = (char*)d_ws;
    unsigned short* Wc  = (unsigned short*)ws;                 // 1,146,880 B
    float* biasc        = (float*)(ws + 1146880);              // 3584 B
    float* hUc          = (float*)(ws + 1150464);              // 3584 B
    unsigned short* hb  = (unsigned short*)(ws + 1154112);     // 22,369,536 B

    float* outh = (float*)d_out;
    float* outc = outh + (size_t)NNODES * 128;

    hipLaunchKernelGGL(prep, dim3(1232), dim3(512), 0, stream,
                       W_iou, U_iou, W_f, U_f, b_iou, b_uiou, b_wf, b_uf, h0,
                       Wc, biasc, hUc);

    // level 8 (leaf): 65536 nodes, BM=32
    hipLaunchKernelGGL(tree_leaf32, dim3(2048), dim3(512), 0, stream,
                       emb, Wc, hUc, c0, outh, outc, hb);

    // levels 7..3 via dsplit
    const int ns[5]   = {16384, 4096, 1024, 256, 64};
    const int offs[5] = {65536, 81920, 86016, 87040, 87296};
    const int cbs[5]  = {0, 65536, 81920, 86016, 87040};
    for (int li = 0; li < 5; ++li) {
        const int units = (ns[li] / 32) * 8;
        hipLaunchKernelGGL(tree_dsplit, dim3(units), dim3(512), 0, stream,
                           emb, Wc, biasc, outh, outc, hb,
                           ns[li], offs[li], cbs[li]);
    }

    // levels 2..0 in one block
    hipLaunchKernelGGL(tree_tail3, dim3(1), dim3(512), 0, stream,
                       emb, Wc, biasc, outh, outc, hb);
}